// Round 7
// baseline (6499.700 us; speedup 1.0000x reference)
//
#include <hip/hip_runtime.h>
#include <hip/hip_fp16.h>

typedef _Float16 f16;
typedef unsigned int u32;
typedef unsigned long long u64;
typedef _Float16 f16x8 __attribute__((ext_vector_type(8)));
typedef float f32x4 __attribute__((ext_vector_type(4)));

#define B_ 64
#define T_ 512
#define I_ 512
#define H_ 1024
#define HB_ (B_ * H_)
#define NWG_ 192
#define STEPS_ (T_ + 2)
#define SLOT_ 65536   // u32 elements per ring slot (64 rows x 1024 cols)

// ---- agent-scope (LLC-coherent) helpers: compiler picks the encodings ----
__device__ __forceinline__ u64 lda64(const u32* p) {
    return __hip_atomic_load((const u64*)p, __ATOMIC_RELAXED, __HIP_MEMORY_SCOPE_AGENT);
}
__device__ __forceinline__ u32 lda32(const u32* p) {
    return __hip_atomic_load(p, __ATOMIC_RELAXED, __HIP_MEMORY_SCOPE_AGENT);
}
__device__ __forceinline__ void sta32(u32* p, u32 v) {
    __hip_atomic_store(p, v, __ATOMIC_RELAXED, __HIP_MEMORY_SCOPE_AGENT);
}
__device__ __forceinline__ u32 packhl(float v) {
    f16 h = (f16)v; f16 l = (f16)(v - (float)h);
    return (u32)__builtin_bit_cast(unsigned short, h)
         | ((u32)__builtin_bit_cast(unsigned short, l) << 16);
}

// ---------------- conversion kernels ----------------
__global__ void cvt_f16(const float* __restrict__ s, f16* __restrict__ d, long n) {
    long i = ((long)blockIdx.x * blockDim.x + threadIdx.x) * 4;
    long stride = (long)gridDim.x * blockDim.x * 4;
    for (; i < n; i += stride) {
        float4 v = *reinterpret_cast<const float4*>(s + i);
        d[i+0] = (f16)v.x; d[i+1] = (f16)v.y; d[i+2] = (f16)v.z; d[i+3] = (f16)v.w;
    }
}

__global__ void init_rings(const float* __restrict__ h0,
                           u32* __restrict__ ring0, u32* __restrict__ ring1) {
    int i = blockIdx.x * blockDim.x + threadIdx.x;   // 0..HB_-1
    ring0[SLOT_ + i] = packhl(h0[i]);
    ring1[SLOT_ + i] = packhl(h0[HB_ + i]);
}

// ---------------- xproj0 GEMM: 4 n-tiles per wave ----------------
__global__ __launch_bounds__(256) void gemm_xproj(
    const f16* __restrict__ A, const f16* __restrict__ W,
    const float* __restrict__ bias, f16* __restrict__ out)
{
    const int wave = threadIdx.x >> 6, lane = threadIdx.x & 63;
    const int m0 = blockIdx.x << 4;
    const int r = lane & 15, kq = lane >> 4;
    const int ngrp = (blockIdx.y << 8) + (wave << 6);
    const f16* pa = A + (long)(m0 + r) * I_ + kq * 8;
    const f16* pw = W + (long)(ngrp + r) * I_ + kq * 8;

    f32x4 acc[4] = {};
    #pragma unroll
    for (int kc = 0; kc < I_; kc += 32) {
        f16x8 af = *reinterpret_cast<const f16x8*>(pa + kc);
        #pragma unroll
        for (int t = 0; t < 4; ++t) {
            f16x8 wf = *reinterpret_cast<const f16x8*>(pw + (long)t * 16 * I_ + kc);
            acc[t] = __builtin_amdgcn_mfma_f32_16x16x32_f16(af, wf, acc[t], 0, 0, 0);
        }
    }
    const int col = lane & 15, rq = lane >> 4;
    #pragma unroll
    for (int t = 0; t < 4; ++t) {
        const int n = ngrp + t * 16 + col;
        const float bv = bias[n];
        #pragma unroll
        for (int j = 0; j < 4; ++j)
            out[(long)(m0 + rq * 4 + j) * H_ + n] = (f16)(acc[t][j] + bv);
    }
}

// ---------------- persistent pipelined scan (round-4 sync, LDS-W) ----------------
// 192 WGs x 256 threads, 3 groups of 64:
//   grp0: h0[s]   = tanh(xp0[s]   + h0[s-1]@Whh0^T)   (hi+lo MFMA)
//   grp1: xp1[s-1]= h0[s-1]@Wxh1^T + b1               (hi only)
//   grp2: h1[s-2] = tanh(xp1[s-2] + h1[s-3]@Whh1^T)   (hi+lo)
// WG: 16 rows x 64 cols; wave w = K-quarter; W slice (64x1024 f16 = 128 KB)
// lives in LDS (immune to fence invalidation), XOR-swizzled 16B chunks.
// Rings pack h as u32 (hi|lo<<16); all ring/xp1 traffic = relaxed agent atomics
// (LLC-coherent, L2-bypassing). Barrier identical to the proven round-4 one.
__global__ void __launch_bounds__(256, 1) rnn_scan(
    const f16* __restrict__ Whh0, const f16* __restrict__ Wxh1, const f16* __restrict__ Whh1,
    const f16* __restrict__ xp0, const float* __restrict__ b1,
    u32* __restrict__ ring0, u32* __restrict__ ring1, u32* __restrict__ xp1,
    float* __restrict__ out, int* __restrict__ flags)
{
    extern __shared__ char smem[];                 // 128 KB W + 16 KB part
    float* part = (float*)(smem + 131072);

    const int tid = threadIdx.x;
    const int wave = tid >> 6, lane = tid & 63;
    const int wg = blockIdx.x;
    const int grp = wg >> 6, sub = wg & 63;
    const int m0 = (sub & 3) << 4;
    const int nbase = (sub >> 2) << 6;
    const int r = lane & 15, kq = lane >> 4;       // A-row / k-quad; also finalize col/row-quad
    const int kbase = wave << 8;

    const f16* Wmat = (grp == 0) ? Whh0 : (grp == 1) ? Wxh1 : Whh1;

    // ---- one-time: stage W slice into LDS (swizzled 16B chunks) ----
    for (int i = 0; i < 32; ++i) {
        int idx = tid + (i << 8);                  // 0..8191
        int row = idx >> 7, c = idx & 127;         // row 0..63, chunk 0..127
        f32x4 v = *reinterpret_cast<const f32x4*>(Wmat + (long)(nbase + row) * H_ + (c << 3));
        *reinterpret_cast<f32x4*>(smem + row * 2048 + ((c ^ (row & 7)) << 4)) = v;
    }
    __syncthreads();

    const int nf = nbase + (wave << 4) + r;        // finalize column (wave w -> tile w)
    const float b1v = (grp == 1) ? b1[nf] : 0.f;

    for (int s = 0; s < STEPS_; ++s) {
        int ts; bool active;
        const u32* ringA;
        if (grp == 0) {
            ts = s; active = (ts < T_);
            ringA = ring0 + (((ts - 1) & 1) ? SLOT_ : 0);
        } else if (grp == 1) {
            ts = s - 1; active = (ts >= 0) && (ts < T_);
            ringA = ring0 + ((ts & 1) ? SLOT_ : 0);
        } else {
            ts = s - 2; active = (ts >= 0) && (ts < T_);
            ringA = ring1 + (((ts - 1) & 1) ? SLOT_ : 0);
        }

        float xv[4] = {0.f, 0.f, 0.f, 0.f};
        if (active) {
            // early finalize-operand loads
            if (grp == 0) {
                #pragma unroll
                for (int j = 0; j < 4; ++j)
                    xv[j] = (float)xp0[((long)(m0 + kq * 4 + j) * T_ + ts) * H_ + nf];
            } else if (grp == 2) {
                #pragma unroll
                for (int j = 0; j < 4; ++j)
                    xv[j] = __builtin_bit_cast(float,
                        lda32(xp1 + ((ts & 1) ? SLOT_ : 0) + (m0 + kq * 4 + j) * 1024 + nf));
            }

            // ring loads: packed u32 rows; lane's k-slice = kbase + it*32 + kq*8 + {0..7}
            const u32* abase = ringA + (m0 + r) * 1024 + kbase + kq * 8;
            u64 q[8][4];
            #pragma unroll
            for (int it = 0; it < 8; ++it)
                #pragma unroll
                for (int c4 = 0; c4 < 4; ++c4)
                    q[it][c4] = lda64(abase + it * 32 + c4 * 2);

            f16x8 ah[8], al[8];
            #pragma unroll
            for (int it = 0; it < 8; ++it)
                #pragma unroll
                for (int c4 = 0; c4 < 4; ++c4) {
                    u32 wlo = (u32)q[it][c4], whi = (u32)(q[it][c4] >> 32);
                    ah[it][c4*2]   = __builtin_bit_cast(f16, (unsigned short)(wlo & 0xffff));
                    ah[it][c4*2+1] = __builtin_bit_cast(f16, (unsigned short)(whi & 0xffff));
                    al[it][c4*2]   = __builtin_bit_cast(f16, (unsigned short)(wlo >> 16));
                    al[it][c4*2+1] = __builtin_bit_cast(f16, (unsigned short)(whi >> 16));
                }

            f32x4 acc[4] = {};
            #pragma unroll
            for (int it = 0; it < 8; ++it) {
                #pragma unroll
                for (int t = 0; t < 4; ++t) {
                    f16x8 wf = *reinterpret_cast<const f16x8*>(
                        smem + (t * 16 + r) * 2048
                             + ((((wave << 5) + (it << 2) + kq) ^ (r & 7)) << 4));
                    acc[t] = __builtin_amdgcn_mfma_f32_16x16x32_f16(ah[it], wf, acc[t], 0, 0, 0);
                    if (grp != 1)
                        acc[t] = __builtin_amdgcn_mfma_f32_16x16x32_f16(al[it], wf, acc[t], 0, 0, 0);
                }
            }
            #pragma unroll
            for (int t = 0; t < 4; ++t)
                *reinterpret_cast<f32x4*>(&part[((wave << 2) + t) * 256 + (lane << 2)]) = acc[t];
        }
        __syncthreads();
        if (active) {
            f32x4 sm = *reinterpret_cast<f32x4*>(&part[wave * 256 + (lane << 2)]);
            #pragma unroll
            for (int w2 = 1; w2 < 4; ++w2)
                sm = sm + *reinterpret_cast<f32x4*>(&part[((w2 << 2) + wave) * 256 + (lane << 2)]);
            #pragma unroll
            for (int j = 0; j < 4; ++j) {
                const int b = m0 + kq * 4 + j;
                const int ri = b * 1024 + nf;
                float v = sm[j];
                if (grp == 0) {
                    v = tanhf(v + xv[j]);
                    sta32(ring0 + ((ts & 1) ? SLOT_ : 0) + ri, packhl(v));
                    if (ts == T_ - 1) out[(long)B_ * T_ * H_ + (long)b * H_ + nf] = v;
                } else if (grp == 1) {
                    sta32(xp1 + ((ts & 1) ? SLOT_ : 0) + ri, __builtin_bit_cast(u32, v + b1v));
                } else {
                    v = tanhf(v + xv[j]);
                    sta32(ring1 + ((ts & 1) ? SLOT_ : 0) + ri, packhl(v));
                    out[((long)b * T_ + ts) * H_ + nf] = v;
                    if (ts == T_ - 1) out[(long)B_ * T_ * H_ + HB_ + (long)b * H_ + nf] = v;
                }
            }
        }
        // ---- proven grid barrier (round 4): fences + per-WG flag + parallel poll ----
        __syncthreads();
        if (tid == 0) {
            __builtin_amdgcn_fence(__ATOMIC_RELEASE, "agent");
            __hip_atomic_store(&flags[wg * 32], s + 1, __ATOMIC_RELAXED, __HIP_MEMORY_SCOPE_AGENT);
        }
        if (tid < NWG_) {
            while (__hip_atomic_load(&flags[tid * 32], __ATOMIC_RELAXED, __HIP_MEMORY_SCOPE_AGENT) < s + 1) {}
        }
        __syncthreads();
        if (tid == 0) {
            __builtin_amdgcn_fence(__ATOMIC_ACQUIRE, "agent");
        }
        __syncthreads();
    }
}

// ---------------- host launcher ----------------
extern "C" void kernel_launch(void* const* d_in, const int* in_sizes, int n_in,
                              void* d_out, int out_size, void* d_ws, size_t ws_size,
                              hipStream_t stream) {
    const float* x    = (const float*)d_in[0];
    const float* h0   = (const float*)d_in[1];
    const float* Wxh0 = (const float*)d_in[2];
    const float* Whh0 = (const float*)d_in[3];
    const float* b0   = (const float*)d_in[4];
    const float* Wxh1 = (const float*)d_in[5];
    const float* Whh1 = (const float*)d_in[6];
    const float* b1   = (const float*)d_in[7];
    float* out = (float*)d_out;

    char* ws = (char*)d_ws;
    const long MB = 1024 * 1024;
    f16* Whh0h = (f16*)(ws + 0);            // 2 MB
    f16* Wxh1h = (f16*)(ws + 2*MB);         // 2 MB
    f16* Whh1h = (f16*)(ws + 4*MB);         // 2 MB
    f16* Wxh0h = (f16*)(ws + 6*MB);         // 1 MB
    int* flags = (int*)(ws + 7*MB);         // 192*32 ints padded
    u32* ring0 = (u32*)(ws + 8*MB);         // [2][64][1024] u32, 512 KB
    u32* ring1 = (u32*)(ws + 8*MB + 512*1024);
    u32* xp1   = (u32*)(ws + 9*MB);         // [2][64][1024] f32-as-u32, 512 KB
    f16* xp0   = (f16*)(ws + 16*MB);        // [B][T][H] f16, 64 MB
    f16* xh    = (f16*)(ws + 80*MB);        // [B][T][I] f16, 32 MB

    cvt_f16<<<512, 256, 0, stream>>>(Whh0, Whh0h, (long)H_*H_);
    cvt_f16<<<512, 256, 0, stream>>>(Wxh1, Wxh1h, (long)H_*H_);
    cvt_f16<<<512, 256, 0, stream>>>(Whh1, Whh1h, (long)H_*H_);
    cvt_f16<<<512, 256, 0, stream>>>(Wxh0, Wxh0h, (long)H_*I_);
    cvt_f16<<<4096, 256, 0, stream>>>(x, xh, (long)B_*T_*I_);
    init_rings<<<HB_/256, 256, 0, stream>>>(h0, ring0, ring1);
    hipMemsetAsync(flags, 0, 32*1024, stream);

    // xp0 = xh @ Wxh0^T + b0   (row index = b*T + t)
    gemm_xproj<<<dim3((B_*T_)/16, H_/256), 256, 0, stream>>>(xh, Wxh0h, b0, xp0);

    hipFuncSetAttribute((const void*)rnn_scan,
                        hipFuncAttributeMaxDynamicSharedMemorySize, 147456);

    void* args[] = { (void*)&Whh0h, (void*)&Wxh1h, (void*)&Whh1h, (void*)&xp0,
                     (void*)&b1, (void*)&ring0, (void*)&ring1, (void*)&xp1,
                     (void*)&out, (void*)&flags };
    hipLaunchCooperativeKernel((void*)rnn_scan, dim3(NWG_), dim3(256), args,
                               147456, stream);
}

// Round 8
// 4156.421 us; speedup vs baseline: 1.5638x; 1.5638x over previous
//
#include <hip/hip_runtime.h>
#include <hip/hip_fp16.h>

typedef _Float16 f16;
typedef unsigned int u32;
typedef unsigned long long u64;
typedef _Float16 f16x8 __attribute__((ext_vector_type(8)));
typedef float f32x4 __attribute__((ext_vector_type(4)));

#define B_ 64
#define T_ 512
#define I_ 512
#define H_ 1024
#define HB_ (B_ * H_)
#define NWG_ 192
#define STEPS_ (T_ + 2)
#define SLOT_ 65536   // u32 elements per ring slot (64 rows x 1024 cols)

// ---- agent-scope (LLC-coherent) helpers: compiler picks the encodings ----
__device__ __forceinline__ u64 lda64(const u32* p) {
    return __hip_atomic_load((const u64*)p, __ATOMIC_RELAXED, __HIP_MEMORY_SCOPE_AGENT);
}
__device__ __forceinline__ u32 lda32(const u32* p) {
    return __hip_atomic_load(p, __ATOMIC_RELAXED, __HIP_MEMORY_SCOPE_AGENT);
}
__device__ __forceinline__ void sta32(u32* p, u32 v) {
    __hip_atomic_store(p, v, __ATOMIC_RELAXED, __HIP_MEMORY_SCOPE_AGENT);
}
__device__ __forceinline__ u32 packhl(float v) {
    f16 h = (f16)v; f16 l = (f16)(v - (float)h);
    return (u32)__builtin_bit_cast(unsigned short, h)
         | ((u32)__builtin_bit_cast(unsigned short, l) << 16);
}

// ---------------- conversion kernels ----------------
__global__ void cvt_f16(const float* __restrict__ s, f16* __restrict__ d, long n) {
    long i = ((long)blockIdx.x * blockDim.x + threadIdx.x) * 4;
    long stride = (long)gridDim.x * blockDim.x * 4;
    for (; i < n; i += stride) {
        float4 v = *reinterpret_cast<const float4*>(s + i);
        d[i+0] = (f16)v.x; d[i+1] = (f16)v.y; d[i+2] = (f16)v.z; d[i+3] = (f16)v.w;
    }
}

__global__ void init_rings(const float* __restrict__ h0,
                           u32* __restrict__ ring0, u32* __restrict__ ring1) {
    int i = blockIdx.x * blockDim.x + threadIdx.x;   // 0..HB_-1
    ring0[SLOT_ + i] = packhl(h0[i]);
    ring1[SLOT_ + i] = packhl(h0[HB_ + i]);
}

// ---------------- xproj0 GEMM: 4 n-tiles per wave ----------------
__global__ __launch_bounds__(256) void gemm_xproj(
    const f16* __restrict__ A, const f16* __restrict__ W,
    const float* __restrict__ bias, f16* __restrict__ out)
{
    const int wave = threadIdx.x >> 6, lane = threadIdx.x & 63;
    const int m0 = blockIdx.x << 4;
    const int r = lane & 15, kq = lane >> 4;
    const int ngrp = (blockIdx.y << 8) + (wave << 6);
    const f16* pa = A + (long)(m0 + r) * I_ + kq * 8;
    const f16* pw = W + (long)(ngrp + r) * I_ + kq * 8;

    f32x4 acc[4] = {};
    #pragma unroll
    for (int kc = 0; kc < I_; kc += 32) {
        f16x8 af = *reinterpret_cast<const f16x8*>(pa + kc);
        #pragma unroll
        for (int t = 0; t < 4; ++t) {
            f16x8 wf = *reinterpret_cast<const f16x8*>(pw + (long)t * 16 * I_ + kc);
            acc[t] = __builtin_amdgcn_mfma_f32_16x16x32_f16(af, wf, acc[t], 0, 0, 0);
        }
    }
    const int col = lane & 15, rq = lane >> 4;
    #pragma unroll
    for (int t = 0; t < 4; ++t) {
        const int n = ngrp + t * 16 + col;
        const float bv = bias[n];
        #pragma unroll
        for (int j = 0; j < 4; ++j)
            out[(long)(m0 + rq * 4 + j) * H_ + n] = (f16)(acc[t][j] + bv);
    }
}

// ---------------- persistent pipelined scan ----------------
// Same data path as the passing round-7 kernel (LDS-resident W, packed u32
// hi/lo rings via relaxed agent atomics). Changes:
//  (a) NO per-step release/acquire fences — all cross-step data is agent-
//      atomic (LLC-coherent); ordering data->flag via vmcnt(0)+syncthreads
//      (data stores retired at the LLC before the flag store is issued).
//  (b) Two-level barrier: WG0's threads 0..191 poll one per-WG flag each;
//      tid0 of WG0 then publishes a single `go` word; all other WGs poll
//      only that one cacheline. Kills the 192x192 distinct-line poll storm.
__global__ void __launch_bounds__(256, 1) rnn_scan(
    const f16* __restrict__ Whh0, const f16* __restrict__ Wxh1, const f16* __restrict__ Whh1,
    const f16* __restrict__ xp0, const float* __restrict__ b1,
    u32* __restrict__ ring0, u32* __restrict__ ring1, u32* __restrict__ xp1,
    float* __restrict__ out, int* __restrict__ flags, int* __restrict__ go)
{
    extern __shared__ char smem[];                 // 128 KB W + 16 KB part
    float* part = (float*)(smem + 131072);

    const int tid = threadIdx.x;
    const int wave = tid >> 6, lane = tid & 63;
    const int wg = blockIdx.x;
    const int grp = wg >> 6, sub = wg & 63;
    const int m0 = (sub & 3) << 4;
    const int nbase = (sub >> 2) << 6;
    const int r = lane & 15, kq = lane >> 4;
    const int kbase = wave << 8;

    const f16* Wmat = (grp == 0) ? Whh0 : (grp == 1) ? Wxh1 : Whh1;

    // ---- one-time: stage W slice into LDS (swizzled 16B chunks) ----
    for (int i = 0; i < 32; ++i) {
        int idx = tid + (i << 8);                  // 0..8191
        int row = idx >> 7, c = idx & 127;         // row 0..63, chunk 0..127
        f32x4 v = *reinterpret_cast<const f32x4*>(Wmat + (long)(nbase + row) * H_ + (c << 3));
        *reinterpret_cast<f32x4*>(smem + row * 2048 + ((c ^ (row & 7)) << 4)) = v;
    }
    __syncthreads();

    const int nf = nbase + (wave << 4) + r;        // finalize column (wave w -> tile w)
    const float b1v = (grp == 1) ? b1[nf] : 0.f;

    for (int s = 0; s < STEPS_; ++s) {
        int ts; bool active;
        const u32* ringA;
        if (grp == 0) {
            ts = s; active = (ts < T_);
            ringA = ring0 + (((ts - 1) & 1) ? SLOT_ : 0);
        } else if (grp == 1) {
            ts = s - 1; active = (ts >= 0) && (ts < T_);
            ringA = ring0 + ((ts & 1) ? SLOT_ : 0);
        } else {
            ts = s - 2; active = (ts >= 0) && (ts < T_);
            ringA = ring1 + (((ts - 1) & 1) ? SLOT_ : 0);
        }

        float xv[4] = {0.f, 0.f, 0.f, 0.f};
        if (active) {
            // early finalize-operand loads
            if (grp == 0) {
                #pragma unroll
                for (int j = 0; j < 4; ++j)
                    xv[j] = (float)xp0[((long)(m0 + kq * 4 + j) * T_ + ts) * H_ + nf];
            } else if (grp == 2) {
                #pragma unroll
                for (int j = 0; j < 4; ++j)
                    xv[j] = __builtin_bit_cast(float,
                        lda32(xp1 + ((ts & 1) ? SLOT_ : 0) + (m0 + kq * 4 + j) * 1024 + nf));
            }

            // ring loads: packed u32 rows; lane's k-slice = kbase + it*32 + kq*8 + {0..7}
            const u32* abase = ringA + (m0 + r) * 1024 + kbase + kq * 8;
            u64 q[8][4];
            #pragma unroll
            for (int it = 0; it < 8; ++it)
                #pragma unroll
                for (int c4 = 0; c4 < 4; ++c4)
                    q[it][c4] = lda64(abase + it * 32 + c4 * 2);

            f16x8 ah[8], al[8];
            #pragma unroll
            for (int it = 0; it < 8; ++it)
                #pragma unroll
                for (int c4 = 0; c4 < 4; ++c4) {
                    u32 wlo = (u32)q[it][c4], whi = (u32)(q[it][c4] >> 32);
                    ah[it][c4*2]   = __builtin_bit_cast(f16, (unsigned short)(wlo & 0xffff));
                    ah[it][c4*2+1] = __builtin_bit_cast(f16, (unsigned short)(whi & 0xffff));
                    al[it][c4*2]   = __builtin_bit_cast(f16, (unsigned short)(wlo >> 16));
                    al[it][c4*2+1] = __builtin_bit_cast(f16, (unsigned short)(whi >> 16));
                }

            f32x4 acc[4] = {};
            #pragma unroll
            for (int it = 0; it < 8; ++it) {
                #pragma unroll
                for (int t = 0; t < 4; ++t) {
                    f16x8 wf = *reinterpret_cast<const f16x8*>(
                        smem + (t * 16 + r) * 2048
                             + ((((wave << 5) + (it << 2) + kq) ^ (r & 7)) << 4));
                    acc[t] = __builtin_amdgcn_mfma_f32_16x16x32_f16(ah[it], wf, acc[t], 0, 0, 0);
                    if (grp != 1)
                        acc[t] = __builtin_amdgcn_mfma_f32_16x16x32_f16(al[it], wf, acc[t], 0, 0, 0);
                }
            }
            #pragma unroll
            for (int t = 0; t < 4; ++t)
                *reinterpret_cast<f32x4*>(&part[((wave << 2) + t) * 256 + (lane << 2)]) = acc[t];
        }
        __syncthreads();
        if (active) {
            f32x4 sm = *reinterpret_cast<f32x4*>(&part[wave * 256 + (lane << 2)]);
            #pragma unroll
            for (int w2 = 1; w2 < 4; ++w2)
                sm = sm + *reinterpret_cast<f32x4*>(&part[((w2 << 2) + wave) * 256 + (lane << 2)]);
            #pragma unroll
            for (int j = 0; j < 4; ++j) {
                const int b = m0 + kq * 4 + j;
                const int ri = b * 1024 + nf;
                float v = sm[j];
                if (grp == 0) {
                    v = tanhf(v + xv[j]);
                    sta32(ring0 + ((ts & 1) ? SLOT_ : 0) + ri, packhl(v));
                    if (ts == T_ - 1) out[(long)B_ * T_ * H_ + (long)b * H_ + nf] = v;
                } else if (grp == 1) {
                    sta32(xp1 + ((ts & 1) ? SLOT_ : 0) + ri, __builtin_bit_cast(u32, v + b1v));
                } else {
                    v = tanhf(v + xv[j]);
                    sta32(ring1 + ((ts & 1) ? SLOT_ : 0) + ri, packhl(v));
                    out[((long)b * T_ + ts) * H_ + nf] = v;
                    if (ts == T_ - 1) out[(long)B_ * T_ * H_ + HB_ + (long)b * H_ + nf] = v;
                }
            }
        }
        // ---- two-level fence-free barrier ----
        // all data stores (agent atomics -> LLC) retired before flag store:
        asm volatile("s_waitcnt vmcnt(0)" ::: "memory");
        __syncthreads();
        if (tid == 0)
            __hip_atomic_store(&flags[wg * 32], s + 1, __ATOMIC_RELAXED, __HIP_MEMORY_SCOPE_AGENT);
        if (wg == 0) {
            if (tid < NWG_) {
                int g = 0;
                while (__hip_atomic_load(&flags[tid * 32], __ATOMIC_RELAXED, __HIP_MEMORY_SCOPE_AGENT) < s + 1)
                    if (++g > (1 << 22)) break;   // visible-fail guard
            }
            __syncthreads();
            if (tid == 0)
                __hip_atomic_store(go, s + 1, __ATOMIC_RELAXED, __HIP_MEMORY_SCOPE_AGENT);
        } else {
            if (tid == 0) {
                int g = 0;
                while (__hip_atomic_load(go, __ATOMIC_RELAXED, __HIP_MEMORY_SCOPE_AGENT) < s + 1)
                    if (++g > (1 << 22)) break;
            }
        }
        __syncthreads();
        asm volatile("" ::: "memory");   // pin next-step loads behind the poll
    }
}

// ---------------- host launcher ----------------
extern "C" void kernel_launch(void* const* d_in, const int* in_sizes, int n_in,
                              void* d_out, int out_size, void* d_ws, size_t ws_size,
                              hipStream_t stream) {
    const float* x    = (const float*)d_in[0];
    const float* h0   = (const float*)d_in[1];
    const float* Wxh0 = (const float*)d_in[2];
    const float* Whh0 = (const float*)d_in[3];
    const float* b0   = (const float*)d_in[4];
    const float* Wxh1 = (const float*)d_in[5];
    const float* Whh1 = (const float*)d_in[6];
    const float* b1   = (const float*)d_in[7];
    float* out = (float*)d_out;

    char* ws = (char*)d_ws;
    const long MB = 1024 * 1024;
    f16* Whh0h = (f16*)(ws + 0);            // 2 MB
    f16* Wxh1h = (f16*)(ws + 2*MB);         // 2 MB
    f16* Whh1h = (f16*)(ws + 4*MB);         // 2 MB
    f16* Wxh0h = (f16*)(ws + 6*MB);         // 1 MB
    int* flags = (int*)(ws + 7*MB);         // 192*32 ints padded
    int* go    = (int*)(ws + 7*MB + 28*1024);
    u32* ring0 = (u32*)(ws + 8*MB);         // [2][64][1024] u32, 512 KB
    u32* ring1 = (u32*)(ws + 8*MB + 512*1024);
    u32* xp1   = (u32*)(ws + 9*MB);         // [2][64][1024] f32-as-u32, 512 KB
    f16* xp0   = (f16*)(ws + 16*MB);        // [B][T][H] f16, 64 MB
    f16* xh    = (f16*)(ws + 80*MB);        // [B][T][I] f16, 32 MB

    cvt_f16<<<512, 256, 0, stream>>>(Whh0, Whh0h, (long)H_*H_);
    cvt_f16<<<512, 256, 0, stream>>>(Wxh1, Wxh1h, (long)H_*H_);
    cvt_f16<<<512, 256, 0, stream>>>(Whh1, Whh1h, (long)H_*H_);
    cvt_f16<<<512, 256, 0, stream>>>(Wxh0, Wxh0h, (long)H_*I_);
    cvt_f16<<<4096, 256, 0, stream>>>(x, xh, (long)B_*T_*I_);
    init_rings<<<HB_/256, 256, 0, stream>>>(h0, ring0, ring1);
    hipMemsetAsync(flags, 0, 32*1024, stream);

    // xp0 = xh @ Wxh0^T + b0   (row index = b*T + t)
    gemm_xproj<<<dim3((B_*T_)/16, H_/256), 256, 0, stream>>>(xh, Wxh0h, b0, xp0);

    hipFuncSetAttribute((const void*)rnn_scan,
                        hipFuncAttributeMaxDynamicSharedMemorySize, 147456);

    void* args[] = { (void*)&Whh0h, (void*)&Wxh1h, (void*)&Whh1h, (void*)&xp0,
                     (void*)&b1, (void*)&ring0, (void*)&ring1, (void*)&xp1,
                     (void*)&out, (void*)&flags, (void*)&go };
    hipLaunchCooperativeKernel((void*)rnn_scan, dim3(NWG_), dim3(256), args,
                               147456, stream);
}